// Round 5
// baseline (155.268 us; speedup 1.0000x reference)
//
#include <hip/hip_runtime.h>

#define IMG_H 512
#define IMG_W 512
#define TW 64    // output tile width
#define TH 32    // output tile height
#define GH 38    // gray rows staged (TH + 6 halo)
#define AS 72    // gray LDS stride (ushort, bf16)
#define VS 72    // V1/V2 LDS stride (ushort, bf16)

__device__ __forceinline__ int reflect(int i, int n) {
    i = (i < 0) ? -i : i;
    return (i >= n) ? (2 * n - 2 - i) : i;
}
__device__ __forceinline__ float4 ld4s(const float* p) { return *(const float4*)p; }
// bf16 pack (truncate) / unpack
__device__ __forceinline__ ushort pkbf(float f) { return (ushort)(__builtin_bit_cast(unsigned, f) >> 16); }
__device__ __forceinline__ float  upbf(ushort u) { return __builtin_bit_cast(float, (unsigned)u << 16); }

// gray → bf16x4 from 3 rgb float4s
#define GRAY4U(v0, v1, v2, dst) do { \
    ushort4 g_; \
    g_.x = pkbf((v0).x * wr + (v0).y * wg + (v0).z * wb); \
    g_.y = pkbf((v0).w * wr + (v1).x * wg + (v1).y * wb); \
    g_.z = pkbf((v1).z * wr + (v1).w * wg + (v2).x * wb); \
    g_.w = pkbf((v2).y * wr + (v2).z * wg + (v2).w * wb); \
    *(ushort4*)(dst) = g_; \
} while (0)

__global__ __launch_bounds__(256, 8)
void edge_fused_kernel(const float* __restrict__ in, float* __restrict__ out) {
    const int bx0 = blockIdx.x * TW;
    const int by0 = blockIdx.y * TH;
    const int b   = blockIdx.z;
    const int tid = threadIdx.x;

    __shared__ ushort A[GH * AS];    // gray bf16, rows by0-3..by0+34, cols bx0-4..bx0+67
    __shared__ ushort B1[TH * VS];   // V1 = (smooth∘gauss)_v, symmetric 7-tap
    __shared__ ushort B2[TH * VS];   // V2 = (deriv∘gauss)_v, antisymmetric 7-tap

    // gaussian sigma=1.5 k=5: g = [g0,g1,g2,g1,g0]
    const float g0 = 0.12007838f, g1 = 0.23388076f, g2 = 0.29208171f;
    // composed smooth∘gauss (7-tap symmetric): [c3,c2,c1,c0,c1,c2,c3]
    const float c0 = 1.05192494f;  // 2g1+2g2
    const float c1 = 0.87992161f;  // g0+2g1+g2
    const float c2 = 0.47403752f;  // 2g0+g1
    const float c3 = 0.12007838f;  // g0
    // composed deriv∘gauss (7-tap antisym): [-a3,-a2,-a1,0,a1,a2,a3]
    const float a1 = 0.17200333f;  // g2-g0
    const float a2 = 0.23388076f;  // g1
    const float a3 = 0.12007838f;  // g0
    const float wr = 0.2989f, wg = 0.5870f, wb = 0.1140f;

    const float* img = in + (size_t)b * (IMG_H * IMG_W * 3);
    const int gx0 = bx0 - 4;
    const bool left  = (bx0 == 0);
    const bool right = (bx0 + TW == IMG_W);

    // ---- Stage 1: grayscale (bf16) into A[i][j], i in [0,38), j in [0,72) ----
    if (!left && !right) {
        const int idxA = tid, idxB = tid + 256, idxC = tid + 512;
        const int iA = idxA / 18, jA = idxA % 18;
        const int iB = idxB / 18, jB = idxB % 18;
        const int iC = idxC / 18, jC = idxC % 18;
        const bool hasC = (idxC < GH * 18);
        const float* rpA = img + (size_t)reflect(by0 - 3 + iA, IMG_H) * (IMG_W * 3) + (gx0 + 4 * jA) * 3;
        const float* rpB = img + (size_t)reflect(by0 - 3 + iB, IMG_H) * (IMG_W * 3) + (gx0 + 4 * jB) * 3;
        const float4 a0 = ld4s(rpA), a1v = ld4s(rpA + 4), a2v = ld4s(rpA + 8);
        const float4 b0 = ld4s(rpB), b1v = ld4s(rpB + 4), b2v = ld4s(rpB + 8);
        GRAY4U(a0, a1v, a2v, &A[iA * AS + 4 * jA]);
        float4 q0, q1, q2;
        if (hasC) {
            const float* rpC = img + (size_t)reflect(by0 - 3 + iC, IMG_H) * (IMG_W * 3) + (gx0 + 4 * jC) * 3;
            q0 = ld4s(rpC); q1 = ld4s(rpC + 4); q2 = ld4s(rpC + 8);
        }
        GRAY4U(b0, b1v, b2v, &A[iB * AS + 4 * jB]);
        if (hasC) GRAY4U(q0, q1, q2, &A[iC * AS + 4 * jC]);
    } else {
        const int go = left ? 1 : 0;
        for (int idx = tid; idx < GH * 17; idx += 256) {
            const int i = idx / 17, g = idx % 17 + go;
            const int gy = reflect(by0 - 3 + i, IMG_H);
            const float* rp = img + (size_t)gy * (IMG_W * 3) + (gx0 + 4 * g) * 3;
            const float4 v0 = ld4s(rp), v1 = ld4s(rp + 4), v2 = ld4s(rp + 8);
            GRAY4U(v0, v1, v2, &A[i * AS + 4 * g]);
        }
        const int jbase = left ? 0 : 68;
        for (int idx = tid; idx < GH * 4; idx += 256) {
            const int i = idx / 4, j = idx % 4;
            const int gy = reflect(by0 - 3 + i, IMG_H);
            const int gx = reflect(gx0 + jbase + j, IMG_W);
            const float* p = img + (size_t)gy * (IMG_W * 3) + gx * 3;
            A[i * AS + jbase + j] = pkbf(p[0] * wr + p[1] * wg + p[2] * wb);
        }
    }
    __syncthreads();

    // ---- Stage 2: vertical composed 7-taps -> V1, V2 (bf16), 32 rows x 18 groups ----
    {
        const float C1[7] = { c3, c2, c1, c0, c1, c2, c3 };
        const float C2[7] = { -a3, -a2, -a1, 0.0f, a1, a2, a3 };
        for (int t = 0; t < 3; ++t) {
            const int idx = tid + 256 * t;
            if (idx >= TH * 18) break;
            const int r = idx / 18, g = idx % 18;
            const ushort* base = &A[r * AS + 4 * g];
            float v1x = 0, v1y = 0, v1z = 0, v1w = 0;
            float v2x = 0, v2y = 0, v2z = 0, v2w = 0;
            #pragma unroll
            for (int k = 0; k < 7; ++k) {
                const ushort4 xq = *(const ushort4*)(base + k * AS);
                const float x0 = upbf(xq.x), x1 = upbf(xq.y), x2 = upbf(xq.z), x3 = upbf(xq.w);
                v1x = fmaf(C1[k], x0, v1x); v1y = fmaf(C1[k], x1, v1y);
                v1z = fmaf(C1[k], x2, v1z); v1w = fmaf(C1[k], x3, v1w);
                if (k != 3) {
                    v2x = fmaf(C2[k], x0, v2x); v2y = fmaf(C2[k], x1, v2y);
                    v2z = fmaf(C2[k], x2, v2z); v2w = fmaf(C2[k], x3, v2w);
                }
            }
            ushort4 o1, o2;
            o1.x = pkbf(v1x); o1.y = pkbf(v1y); o1.z = pkbf(v1z); o1.w = pkbf(v1w);
            o2.x = pkbf(v2x); o2.y = pkbf(v2y); o2.z = pkbf(v2z); o2.w = pkbf(v2w);
            *(ushort4*)&B1[r * VS + 4 * g] = o1;
            *(ushort4*)&B2[r * VS + 4 * g] = o2;
        }
    }
    __syncthreads();

    // ---- Stage 3: horizontal composed 7-taps + magnitude + threshold ----
    // out px (r, 4g+p): sx = 7-tap antisym on V1, sy = 7-tap sym on V2
    #pragma unroll
    for (int t = 0; t < 2; ++t) {
        const int idx = tid + 256 * t;
        const int r = idx >> 4, g = idx & 15;
        const ushort* p1 = &B1[r * VS + 4 * g];
        const ushort* p2 = &B2[r * VS + 4 * g];
        const ushort4 ua = *(const ushort4*)p1;
        const ushort4 ub = *(const ushort4*)(p1 + 4);
        const ushort4 uc = *(const ushort4*)(p1 + 8);
        const ushort4 wa = *(const ushort4*)p2;
        const ushort4 wb2 = *(const ushort4*)(p2 + 4);
        const ushort4 wc = *(const ushort4*)(p2 + 8);
        float u[12], w[12];
        u[0]=upbf(ua.x); u[1]=upbf(ua.y); u[2]=upbf(ua.z); u[3]=upbf(ua.w);
        u[4]=upbf(ub.x); u[5]=upbf(ub.y); u[6]=upbf(ub.z); u[7]=upbf(ub.w);
        u[8]=upbf(uc.x); u[9]=upbf(uc.y); u[10]=upbf(uc.z); u[11]=upbf(uc.w);
        w[0]=upbf(wa.x); w[1]=upbf(wa.y); w[2]=upbf(wa.z); w[3]=upbf(wa.w);
        w[4]=upbf(wb2.x); w[5]=upbf(wb2.y); w[6]=upbf(wb2.z); w[7]=upbf(wb2.w);
        w[8]=upbf(wc.x); w[9]=upbf(wc.y); w[10]=upbf(wc.z); w[11]=upbf(wc.w);
        float res[4];
        #pragma unroll
        for (int p = 0; p < 4; ++p) {
            const int j = p + 4;  // raw center index (lds col 4g+4+p)
            const float sx = (u[j+3] - u[j-3]) * a3 + (u[j+2] - u[j-2]) * a2 + (u[j+1] - u[j-1]) * a1;
            const float sy = c0 * w[j] + c1 * (w[j-1] + w[j+1]) + c2 * (w[j-2] + w[j+2]) + c3 * (w[j-3] + w[j+3]);
            const float m2 = sx * sx + sy * sy;
            res[p] = (m2 > 900.0f) ? 1.0f : 0.0f;
        }
        float4 rv; rv.x = res[0]; rv.y = res[1]; rv.z = res[2]; rv.w = res[3];
        float* ob = out + (size_t)b * (IMG_H * IMG_W) + (size_t)(by0 + r) * IMG_W + bx0 + 4 * g;
        *(float4*)ob = rv;
    }
}

extern "C" void kernel_launch(void* const* d_in, const int* in_sizes, int n_in,
                              void* d_out, int out_size, void* d_ws, size_t ws_size,
                              hipStream_t stream) {
    const float* in = (const float*)d_in[0];
    float* out = (float*)d_out;
    const int B = in_sizes[0] / (IMG_H * IMG_W * 3);
    dim3 grid(IMG_W / TW, IMG_H / TH, B);
    dim3 block(256, 1, 1);
    edge_fused_kernel<<<grid, block, 0, stream>>>(in, out);
}